// Round 1
// baseline (69.578 us; speedup 1.0000x reference)
//
#include <hip/hip_runtime.h>

#define ALM_DELTA 0.1f

__global__ __launch_bounds__(256) void alm_copy_lambdas(
    const float* __restrict__ lambdas, float* __restrict__ out, int L)
{
    int t = blockIdx.x * blockDim.x + threadIdx.x;
    if (t < L) out[t] = lambdas[t];
}

__global__ __launch_bounds__(256) void alm_qrow_kernel(
    const float* __restrict__ pos, const float* __restrict__ neg,
    const int* __restrict__ idx, const float* __restrict__ lambdas,
    const float* __restrict__ mu, float* __restrict__ out,
    int P, int N, int L)
{
    const int i = blockIdx.x;          // one block per positive sample (row)
    const int t = threadIdx.x;

    const float p_thresh = pos[i] - ALM_DELTA;   // relu(neg - pos + d) = max(0, neg - (pos - d))

    float acc = 0.0f;
    const int n4 = N >> 2;
    const float4* __restrict__ neg4 = (const float4*)neg;
    // coalesced float4 grid-stride over the neg buffer (stays L2-resident)
    for (int k = t; k < n4; k += 256) {
        float4 v = neg4[k];
        acc += fmaxf(v.x - p_thresh, 0.0f);
        acc += fmaxf(v.y - p_thresh, 0.0f);
        acc += fmaxf(v.z - p_thresh, 0.0f);
        acc += fmaxf(v.w - p_thresh, 0.0f);
    }
    // scalar tail (N not multiple of 4)
    for (int j = (n4 << 2) + t; j < N; j += 256) {
        acc += fmaxf(neg[j] - p_thresh, 0.0f);
    }

    // wave-64 shuffle reduction
    #pragma unroll
    for (int off = 32; off > 0; off >>= 1)
        acc += __shfl_down(acc, off, 64);

    __shared__ float ws[4];
    const int wave = t >> 6;
    if ((t & 63) == 0) ws[wave] = acc;
    __syncthreads();

    if (t == 0) {
        float q = ws[0] + ws[1] + ws[2] + ws[3];
        const float m  = mu[0];
        const int   ix = idx[i];
        const float lam = lambdas[ix];          // value BEFORE update
        out[ix] = lam + m * q;                  // unique indices -> plain store
        if (i == P - 1) {
            // loss = (mu/2 * q^2 + lam_last * q) / (P*N), P2_NORM = 1
            float denom = (float)P * (float)N;
            out[L] = (0.5f * m * q * q + lam * q) / denom;
        }
    }
}

extern "C" void kernel_launch(void* const* d_in, const int* in_sizes, int n_in,
                              void* d_out, int out_size, void* d_ws, size_t ws_size,
                              hipStream_t stream) {
    const float* pos     = (const float*)d_in[0];
    const float* neg     = (const float*)d_in[1];
    const int*   idx     = (const int*)  d_in[2];
    const float* lambdas = (const float*)d_in[3];
    const float* mu      = (const float*)d_in[4];
    float* out = (float*)d_out;

    const int P = in_sizes[0];
    const int N = in_sizes[1];
    const int L = in_sizes[3];

    // 1) out[0:L] = lambdas  (covers any index not present in idx)
    alm_copy_lambdas<<<(L + 255) / 256, 256, 0, stream>>>(lambdas, out, L);

    // 2) per-row q reduction + scatter update + loss (stream-ordered after copy)
    alm_qrow_kernel<<<P, 256, 0, stream>>>(pos, neg, idx, lambdas, mu, out, P, N, L);
}

// Round 2
// 67.009 us; speedup vs baseline: 1.0383x; 1.0383x over previous
//
#include <hip/hip_runtime.h>

#define ALM_DELTA 0.1f
#define ROWS 4

__global__ __launch_bounds__(256) void alm_copy_lambdas(
    const float* __restrict__ lambdas, float* __restrict__ out, int L)
{
    int t = blockIdx.x * blockDim.x + threadIdx.x;
    if (t < L) out[t] = lambdas[t];
}

// One block handles ROWS consecutive positive samples: a single sweep over
// `neg` (float4, L1/L2-resident) feeds ROWS accumulators.
__global__ __launch_bounds__(256) void alm_fused_kernel(
    const float* __restrict__ pos, const float* __restrict__ neg,
    const int* __restrict__ idx, const float* __restrict__ lambdas,
    const float* __restrict__ mu, float* __restrict__ out,
    int P, int N, int L)
{
    const int i0 = blockIdx.x * ROWS;
    const int t  = threadIdx.x;

    // relu(neg - pos + d) = max(0, neg - (pos - d)); rows past P get +inf
    // threshold so they contribute 0 and are never stored.
    float pt[ROWS];
    #pragma unroll
    for (int r = 0; r < ROWS; ++r)
        pt[r] = (i0 + r < P) ? (pos[i0 + r] - ALM_DELTA) : 3.4e38f;

    float acc[ROWS];
    #pragma unroll
    for (int r = 0; r < ROWS; ++r) acc[r] = 0.0f;

    const int n4 = N >> 2;
    const float4* __restrict__ neg4 = (const float4*)neg;
    for (int k = t; k < n4; k += 256) {
        float4 v = neg4[k];
        #pragma unroll
        for (int r = 0; r < ROWS; ++r) {
            acc[r] += fmaxf(v.x - pt[r], 0.0f);
            acc[r] += fmaxf(v.y - pt[r], 0.0f);
            acc[r] += fmaxf(v.z - pt[r], 0.0f);
            acc[r] += fmaxf(v.w - pt[r], 0.0f);
        }
    }
    for (int j = (n4 << 2) + t; j < N; j += 256) {
        float x = neg[j];
        #pragma unroll
        for (int r = 0; r < ROWS; ++r)
            acc[r] += fmaxf(x - pt[r], 0.0f);
    }

    // wave-64 shuffle reduction per row
    #pragma unroll
    for (int r = 0; r < ROWS; ++r) {
        #pragma unroll
        for (int off = 32; off > 0; off >>= 1)
            acc[r] += __shfl_down(acc[r], off, 64);
    }

    __shared__ float ws[4][ROWS];
    const int wave = t >> 6;
    if ((t & 63) == 0) {
        #pragma unroll
        for (int r = 0; r < ROWS; ++r) ws[wave][r] = acc[r];
    }
    __syncthreads();

    if (t < ROWS) {
        const int i = i0 + t;
        if (i < P) {
            float q = ws[0][t] + ws[1][t] + ws[2][t] + ws[3][t];
            const float m   = mu[0];
            const int   ix  = idx[i];
            const float lam = lambdas[ix];       // value BEFORE update
            out[ix] = lam + m * q;               // unique indices -> plain store
            if (i == P - 1) {
                float denom = (float)P * (float)N;
                out[L] = (0.5f * m * q * q + lam * q) / denom;
            }
        }
    }
}

extern "C" void kernel_launch(void* const* d_in, const int* in_sizes, int n_in,
                              void* d_out, int out_size, void* d_ws, size_t ws_size,
                              hipStream_t stream) {
    const float* pos     = (const float*)d_in[0];
    const float* neg     = (const float*)d_in[1];
    const int*   idx     = (const int*)  d_in[2];
    const float* lambdas = (const float*)d_in[3];
    const float* mu      = (const float*)d_in[4];
    float* out = (float*)d_out;

    const int P = in_sizes[0];
    const int N = in_sizes[1];
    const int L = in_sizes[3];

    // If the scatter can't cover all of out (P < L), pre-copy lambdas.
    // For the bench shape (P == L, idx a permutation) this is skipped and
    // the whole problem is ONE launch.
    if (P < L)
        alm_copy_lambdas<<<(L + 255) / 256, 256, 0, stream>>>(lambdas, out, L);

    const int blocks = (P + ROWS - 1) / ROWS;
    alm_fused_kernel<<<blocks, 256, 0, stream>>>(pos, neg, idx, lambdas, mu, out, P, N, L);
}

// Round 3
// 66.889 us; speedup vs baseline: 1.0402x; 1.0018x over previous
//
#include <hip/hip_runtime.h>

#define ALM_DELTA 0.1f
#define ROWS 8

__global__ __launch_bounds__(256) void alm_copy_lambdas(
    const float* __restrict__ lambdas, float* __restrict__ out, int L)
{
    int t = blockIdx.x * blockDim.x + threadIdx.x;
    if (t < L) out[t] = lambdas[t];
}

// One block handles ROWS consecutive positive samples: a single sweep over
// `neg` (float4, L2-resident) feeds ROWS accumulators.
// ROWS=8: 512 blocks (2/CU, 8 waves/CU) — halves block count & L2 traffic
// vs ROWS=4 while total VALU work is constant; kernel is latency-bound.
__global__ __launch_bounds__(256) void alm_fused_kernel(
    const float* __restrict__ pos, const float* __restrict__ neg,
    const int* __restrict__ idx, const float* __restrict__ lambdas,
    const float* __restrict__ mu, float* __restrict__ out,
    int P, int N, int L)
{
    const int i0 = blockIdx.x * ROWS;
    const int t  = threadIdx.x;

    // relu(neg - pos + d) = max(0, neg - (pos - d)); rows past P get +inf
    // threshold so they contribute 0 and are never stored.
    float pt[ROWS];
    #pragma unroll
    for (int r = 0; r < ROWS; ++r)
        pt[r] = (i0 + r < P) ? (pos[i0 + r] - ALM_DELTA) : 3.4e38f;

    float acc[ROWS];
    #pragma unroll
    for (int r = 0; r < ROWS; ++r) acc[r] = 0.0f;

    const int n4 = N >> 2;
    const float4* __restrict__ neg4 = (const float4*)neg;
    // unroll 2 -> two outstanding dwordx4 loads per thread to hide L2 latency
    #pragma unroll 2
    for (int k = t; k < n4; k += 256) {
        float4 v = neg4[k];
        #pragma unroll
        for (int r = 0; r < ROWS; ++r) {
            acc[r] += fmaxf(v.x - pt[r], 0.0f);
            acc[r] += fmaxf(v.y - pt[r], 0.0f);
            acc[r] += fmaxf(v.z - pt[r], 0.0f);
            acc[r] += fmaxf(v.w - pt[r], 0.0f);
        }
    }
    for (int j = (n4 << 2) + t; j < N; j += 256) {
        float x = neg[j];
        #pragma unroll
        for (int r = 0; r < ROWS; ++r)
            acc[r] += fmaxf(x - pt[r], 0.0f);
    }

    // wave-64 shuffle reduction per row
    #pragma unroll
    for (int r = 0; r < ROWS; ++r) {
        #pragma unroll
        for (int off = 32; off > 0; off >>= 1)
            acc[r] += __shfl_down(acc[r], off, 64);
    }

    __shared__ float ws[4][ROWS];
    const int wave = t >> 6;
    if ((t & 63) == 0) {
        #pragma unroll
        for (int r = 0; r < ROWS; ++r) ws[wave][r] = acc[r];
    }
    __syncthreads();

    if (t < ROWS) {
        const int i = i0 + t;
        if (i < P) {
            float q = ws[0][t] + ws[1][t] + ws[2][t] + ws[3][t];
            const float m   = mu[0];
            const int   ix  = idx[i];
            const float lam = lambdas[ix];       // value BEFORE update
            out[ix] = lam + m * q;               // unique indices -> plain store
            if (i == P - 1) {
                float denom = (float)P * (float)N;
                out[L] = (0.5f * m * q * q + lam * q) / denom;
            }
        }
    }
}

extern "C" void kernel_launch(void* const* d_in, const int* in_sizes, int n_in,
                              void* d_out, int out_size, void* d_ws, size_t ws_size,
                              hipStream_t stream) {
    const float* pos     = (const float*)d_in[0];
    const float* neg     = (const float*)d_in[1];
    const int*   idx     = (const int*)  d_in[2];
    const float* lambdas = (const float*)d_in[3];
    const float* mu      = (const float*)d_in[4];
    float* out = (float*)d_out;

    const int P = in_sizes[0];
    const int N = in_sizes[1];
    const int L = in_sizes[3];

    // If the scatter can't cover all of out (P < L), pre-copy lambdas.
    // For the bench shape (P == L, idx a permutation) this is skipped and
    // the whole problem is ONE launch.
    if (P < L)
        alm_copy_lambdas<<<(L + 255) / 256, 256, 0, stream>>>(lambdas, out, L);

    const int blocks = (P + ROWS - 1) / ROWS;
    alm_fused_kernel<<<blocks, 256, 0, stream>>>(pos, neg, idx, lambdas, mu, out, P, N, L);
}